// Round 10
// baseline (689.970 us; speedup 1.0000x reference)
//
#include <hip/hip_runtime.h>
#include <hip/hip_bf16.h>
#include <math.h>

#define NN 32768
#define EE 524288
#define FF 32
#define HH 512
#define GG 64
#define CC 10

typedef __attribute__((ext_vector_type(8))) short short8;
typedef __attribute__((ext_vector_type(4))) float floatx4;

__device__ __forceinline__ float bf16_to_f32(unsigned short u) {
    union { unsigned int u; float f; } v;
    v.u = ((unsigned int)u) << 16;
    return v.f;
}
__device__ __forceinline__ unsigned short f32_to_bf16(float f) {
    union { float f; unsigned int u; } v;
    v.f = f;
    unsigned int u = v.u;
    u += 0x7FFFu + ((u >> 16) & 1u);   // round-to-nearest-even
    return (unsigned short)(u >> 16);
}
// tanh(x) = 1 - 2/(1+e^{2x});  exact at +-inf, err far below bf16 grid
__device__ __forceinline__ float fast_tanh(float x) {
    float e = __expf(2.0f * x);
    return 1.0f - 2.0f * __builtin_amdgcn_rcpf(e + 1.0f);
}

// ---------------------------------------------------------------------------
// Merged prep: [0,128) WT0, [128,8320) WTs, [8320,12416) X0 cast
// ---------------------------------------------------------------------------
__global__ void prep_all_kernel(const float* __restrict__ wr0, const float* __restrict__ wl0,
                                unsigned short* __restrict__ WT0,
                                const float* __restrict__ wroot, const float* __restrict__ wrel,
                                unsigned short* __restrict__ WTs,
                                const float* __restrict__ x, unsigned short* __restrict__ X0) {
    const int b = blockIdx.x;
    if (b < 128) {
        int t = b * 256 + threadIdx.x;          // 512*64
        int n = t >> 6, k = t & 63;
        float v = (k < 32) ? wr0[k * 512 + n] : wl0[(k - 32) * 512 + n];
        WT0[t] = f32_to_bf16(v);
    } else if (b < 8320) {
        int t = (b - 128) * 256 + threadIdx.x;  // 4*512*1024
        int l = t >> 19;
        int r = t & 524287;
        int n = r >> 10, k = r & 1023;
        float v = (k < 512) ? wroot[(size_t)l * 262144 + k * 512 + n]
                            : wrel[(size_t)l * 262144 + (k - 512) * 512 + n];
        WTs[t] = f32_to_bf16(v);
    } else {
        int t = (b - 8320) * 256 + threadIdx.x; // NN*32
        int i = t >> 5, c = t & 31;
        X0[(size_t)i * 64 + c] = f32_to_bf16(x[t]);
    }
}

// ---------------------------------------------------------------------------
// CSR build (counting sort of edges by dst) + degree-sort of nodes (LPT:
// descending degree so heavy work first) + permuted CSR.
// ---------------------------------------------------------------------------
__global__ void zero_i32(int* __restrict__ p, int n) {
    int i = blockIdx.x * blockDim.x + threadIdx.x;
    if (i < n) p[i] = 0;
}
__global__ void hist_kernel(const int* __restrict__ dst, int* __restrict__ counts) {
    int e = blockIdx.x * blockDim.x + threadIdx.x;
    if (e < EE) atomicAdd(&counts[dst[e]], 1);
}
__global__ __launch_bounds__(1024) void scan_kernel(const int* __restrict__ counts,
                                                    int* __restrict__ rowStart,
                                                    int* __restrict__ cursor) {
    __shared__ int part[1024];
    const int t = threadIdx.x;
    const int base = t * 32;
    int local[32];
    const int4* cp = (const int4*)(counts + base);
    int s = 0;
#pragma unroll
    for (int ii = 0; ii < 8; ++ii) {
        int4 v = cp[ii];
        local[ii * 4 + 0] = v.x; local[ii * 4 + 1] = v.y;
        local[ii * 4 + 2] = v.z; local[ii * 4 + 3] = v.w;
        s += v.x + v.y + v.z + v.w;
    }
    part[t] = s;
    __syncthreads();
    for (int off = 1; off < 1024; off <<= 1) {
        int v = (t >= off) ? part[t - off] : 0;
        __syncthreads();
        part[t] += v;
        __syncthreads();
    }
    int run = part[t] - s;
#pragma unroll
    for (int i = 0; i < 32; ++i) {
        rowStart[base + i] = run;
        cursor[base + i] = run;
        run += local[i];
    }
    if (t == 1023) rowStart[NN] = run;
}
__global__ void scatter_kernel(const int* __restrict__ src, const int* __restrict__ dst,
                               int* __restrict__ cursor, int* __restrict__ ssrc) {
    int e = blockIdx.x * blockDim.x + threadIdx.x;
    if (e < EE) {
        int p = atomicAdd(&cursor[dst[e]], 1);
        ssrc[p] = src[e];
    }
}
// degree histogram (bin = 255-deg -> descending sort), LDS pre-aggregated
__global__ __launch_bounds__(256) void deg_hist_kernel(const int* __restrict__ counts,
                                                       int* __restrict__ degHist) {
    __shared__ int lh[256];
    lh[threadIdx.x] = 0;
    __syncthreads();
    int i = blockIdx.x * 256 + threadIdx.x;
    int d = counts[i]; if (d > 255) d = 255;
    atomicAdd(&lh[255 - d], 1);
    __syncthreads();
    int v = lh[threadIdx.x];
    if (v) atomicAdd(&degHist[threadIdx.x], v);
}
__global__ __launch_bounds__(256) void deg_scan_kernel(const int* __restrict__ degHist,
                                                       int* __restrict__ degCursor) {
    __shared__ int sh[256];
    const int t = threadIdx.x;
    int own = degHist[t];
    sh[t] = own;
    __syncthreads();
    for (int off = 1; off < 256; off <<= 1) {
        int v = (t >= off) ? sh[t - off] : 0;
        __syncthreads();
        sh[t] += v;
        __syncthreads();
    }
    degCursor[t] = sh[t] - own;   // exclusive prefix
}
// scatter + permuted-degree write (pDeg folded in: one launch fewer)
__global__ __launch_bounds__(256) void deg_scatter_kernel(const int* __restrict__ counts,
                                                          int* __restrict__ degCursor,
                                                          int* __restrict__ perm,
                                                          int* __restrict__ pDeg) {
    __shared__ int lh[256];
    __shared__ int base[256];
    lh[threadIdx.x] = 0;
    __syncthreads();
    int i = blockIdx.x * 256 + threadIdx.x;
    int dtrue = counts[i];
    int d = dtrue > 255 ? 255 : dtrue;
    int bin = 255 - d;
    int lr = atomicAdd(&lh[bin], 1);      // local rank within (block, bin)
    __syncthreads();
    int c = lh[threadIdx.x];
    if (c) base[threadIdx.x] = atomicAdd(&degCursor[threadIdx.x], c);
    __syncthreads();
    int p = base[bin] + lr;
    perm[p] = i;
    pDeg[p] = dtrue;
}
// copy each node's edge list into perm order -> sequential ssrc reads in agg
__global__ __launch_bounds__(256) void edge_copy_kernel(const int* __restrict__ rowStart,
                                                        const int* __restrict__ perm,
                                                        const int* __restrict__ pRowStart,
                                                        const int* __restrict__ ssrc,
                                                        int* __restrict__ pssrc) {
    const int p = blockIdx.x * 4 + (threadIdx.x >> 6);
    const int lane = threadIdx.x & 63;
    const int node = perm[p];
    const int s = rowStart[node], e = rowStart[node + 1];
    const int ns = pRowStart[p];
    for (int j = s + lane; j < e; j += 64) pssrc[ns + (j - s)] = ssrc[j];
}

// ---------------------------------------------------------------------------
__device__ __forceinline__ void acc8(float* a, uint4 d) {
    a[0] += bf16_to_f32((unsigned short)(d.x & 0xFFFFu));
    a[1] += bf16_to_f32((unsigned short)(d.x >> 16));
    a[2] += bf16_to_f32((unsigned short)(d.y & 0xFFFFu));
    a[3] += bf16_to_f32((unsigned short)(d.y >> 16));
    a[4] += bf16_to_f32((unsigned short)(d.z & 0xFFFFu));
    a[5] += bf16_to_f32((unsigned short)(d.z >> 16));
    a[6] += bf16_to_f32((unsigned short)(d.w & 0xFFFFu));
    a[7] += bf16_to_f32((unsigned short)(d.w >> 16));
}

// Generic agg (layer 0, cols=32): one wave per node.
__global__ __launch_bounds__(256) void agg_kernel(const unsigned short* __restrict__ Xh, int ldh,
                                                  int cols, unsigned short* __restrict__ Xagg,
                                                  int ldagg, const int* __restrict__ rowStart,
                                                  const int* __restrict__ ssrc) {
    const int node = blockIdx.x * 4 + (threadIdx.x >> 6);
    const int lane = threadIdx.x & 63;
    const int chunks = cols >> 3;
    if (node >= NN || lane >= chunks) return;
    const int s = rowStart[node];
    const int e = rowStart[node + 1];
    float a[8] = {0.f, 0.f, 0.f, 0.f, 0.f, 0.f, 0.f, 0.f};
    const unsigned short* base = Xh + lane * 8;
    int i = s;
    for (; i + 4 <= e; i += 4) {
        int j0 = ssrc[i], j1 = ssrc[i + 1], j2 = ssrc[i + 2], j3 = ssrc[i + 3];
        uint4 d0 = *(const uint4*)(base + (size_t)j0 * ldh);
        uint4 d1 = *(const uint4*)(base + (size_t)j1 * ldh);
        uint4 d2 = *(const uint4*)(base + (size_t)j2 * ldh);
        uint4 d3 = *(const uint4*)(base + (size_t)j3 * ldh);
        acc8(a, d0); acc8(a, d1); acc8(a, d2); acc8(a, d3);
    }
    for (; i < e; ++i) {
        int j = ssrc[i];
        uint4 d = *(const uint4*)(base + (size_t)j * ldh);
        acc8(a, d);
    }
    unsigned short* out = Xagg + (size_t)node * ldagg + lane * 8;
#pragma unroll
    for (int c = 0; c < 8; ++c) out[c] = f32_to_bf16(a[c]);
}

// ---------------------------------------------------------------------------
// Column-sliced XCD-affine agg (cols=512) v4: persistent blocks (2048 = 8/CU),
// slice fixed per block (XCD affinity), grid-stride over node-chunks (LPT).
// ---------------------------------------------------------------------------
__global__ __launch_bounds__(256) void agg_slice_kernel(const unsigned short* __restrict__ Xh,
                                                        unsigned short* __restrict__ Xagg,
                                                        const int* __restrict__ pRowStart,
                                                        const int* __restrict__ pssrc,
                                                        const int* __restrict__ perm) {
    const int slice = blockIdx.x & 7;
    const int wv = threadIdx.x >> 6;
    const int lane = threadIdx.x & 63;
    const int ln = lane >> 3;
    const int lc = lane & 7;
    const int colOff = slice * 64 + lc * 8;
    const unsigned short* base = Xh + colOff;
    for (int nb = blockIdx.x >> 3; nb < 1024; nb += 256) {
        const int p = nb * 32 + wv * 8 + ln;
        const int node = perm[p];
        const int s = pRowStart[p];
        const int e = pRowStart[p + 1];
        float a[8] = {0.f, 0.f, 0.f, 0.f, 0.f, 0.f, 0.f, 0.f};
        int i = s;
        for (; i + 8 <= e; i += 8) {
            int j0 = pssrc[i], j1 = pssrc[i + 1], j2 = pssrc[i + 2], j3 = pssrc[i + 3];
            int j4 = pssrc[i + 4], j5 = pssrc[i + 5], j6 = pssrc[i + 6], j7 = pssrc[i + 7];
            uint4 d0 = *(const uint4*)(base + (size_t)j0 * 1024);
            uint4 d1 = *(const uint4*)(base + (size_t)j1 * 1024);
            uint4 d2 = *(const uint4*)(base + (size_t)j2 * 1024);
            uint4 d3 = *(const uint4*)(base + (size_t)j3 * 1024);
            uint4 d4 = *(const uint4*)(base + (size_t)j4 * 1024);
            uint4 d5 = *(const uint4*)(base + (size_t)j5 * 1024);
            uint4 d6 = *(const uint4*)(base + (size_t)j6 * 1024);
            uint4 d7 = *(const uint4*)(base + (size_t)j7 * 1024);
            acc8(a, d0); acc8(a, d1); acc8(a, d2); acc8(a, d3);
            acc8(a, d4); acc8(a, d5); acc8(a, d6); acc8(a, d7);
        }
        for (; i < e; ++i) {
            int j = pssrc[i];
            uint4 d = *(const uint4*)(base + (size_t)j * 1024);
            acc8(a, d);
        }
        unsigned short* out = Xagg + (size_t)node * 1024 + colOff;
#pragma unroll
        for (int c = 0; c < 8; ++c) out[c] = f32_to_bf16(a[c]);
    }
}

// ---------------------------------------------------------------------------
// bf16 MFMA GEMM: BK=64, XOR-swizzled LDS. Grid dim3(4,256): bn fastest so
// consecutive blocks share the A-tile (bm) for L2/L3 temporal locality.
// ---------------------------------------------------------------------------
__global__ __launch_bounds__(256, 4) void gemm_bias_tanh(const unsigned short* __restrict__ Xin,
                                                         int ldin, int K,
                                                         const unsigned short* __restrict__ WT,
                                                         const float* __restrict__ bias,
                                                         unsigned short* __restrict__ Xout,
                                                         int ldout) {
    __shared__ __align__(16) unsigned short As[128 * 64];
    __shared__ __align__(16) unsigned short Bs[128 * 64];
    const int tid = threadIdx.x;
    const int lane = tid & 63;
    const int wave = tid >> 6;
    const int wm = wave >> 1, wn = wave & 1;
    const int bm = blockIdx.y, bn = blockIdx.x;

    floatx4 acc[4][4] = {};

    const int lrow = lane >> 3;
    const int schunk = (lane & 7) ^ (lrow & 7);
    const unsigned short* Abase = Xin + (size_t)(bm * 128) * ldin;
    const unsigned short* Bbase = WT + (size_t)(bn * 128) * K;
    const int m = lane & 15;
    const int quad = lane >> 4;

    for (int k0 = 0; k0 < K; k0 += 64) {
        __syncthreads();
#pragma unroll
        for (int q = 0; q < 4; ++q) {
            const int rr = q * 32 + wave * 8;
            const int row = rr + lrow;
            const unsigned short* sa = Abase + (size_t)row * ldin + (k0 + schunk * 8);
            const unsigned short* sb = Bbase + (size_t)row * K + (k0 + schunk * 8);
            __builtin_amdgcn_global_load_lds(
                (const __attribute__((address_space(1))) void*)sa,
                (__attribute__((address_space(3))) void*)(&As[rr * 64]), 16, 0, 0);
            __builtin_amdgcn_global_load_lds(
                (const __attribute__((address_space(1))) void*)sb,
                (__attribute__((address_space(3))) void*)(&Bs[rr * 64]), 16, 0, 0);
        }
        __syncthreads();
#pragma unroll
        for (int half = 0; half < 2; ++half) {
            short8 af[4], bfr[4];
#pragma unroll
            for (int t = 0; t < 4; ++t) {
                const int row = wm * 64 + t * 16 + m;
                const int chunk = (half * 4 + quad) ^ (row & 7);
                af[t] = *(const short8*)&As[row * 64 + chunk * 8];
            }
#pragma unroll
            for (int t = 0; t < 4; ++t) {
                const int row = wn * 64 + t * 16 + m;
                const int chunk = (half * 4 + quad) ^ (row & 7);
                bfr[t] = *(const short8*)&Bs[row * 64 + chunk * 8];
            }
#pragma unroll
            for (int mt = 0; mt < 4; ++mt)
#pragma unroll
                for (int nt = 0; nt < 4; ++nt)
                    acc[mt][nt] = __builtin_amdgcn_mfma_f32_16x16x32_bf16(af[mt], bfr[nt],
                                                                          acc[mt][nt], 0, 0, 0);
        }
    }

    const int row0 = bm * 128 + wm * 64;
    const int col0 = bn * 128 + wn * 64;
#pragma unroll
    for (int mt = 0; mt < 4; ++mt) {
#pragma unroll
        for (int nt = 0; nt < 4; ++nt) {
            const int col = col0 + nt * 16 + m;
            const float bv = bias[col];
#pragma unroll
            for (int r = 0; r < 4; ++r) {
                const int row = row0 + mt * 16 + quad * 4 + r;
                float v = fast_tanh(acc[mt][nt][r] + bv);
                Xout[(size_t)row * ldout + col] = f32_to_bf16(v);
            }
        }
    }
}

// ---------------------------------------------------------------------------
// Pooling: 2-stage (8 row-slices); stage 2 writes TRANSPOSED gbufT[f][graph].
// ---------------------------------------------------------------------------
__global__ __launch_bounds__(256) void pool_partial(const unsigned short* __restrict__ h,
                                                    const int* __restrict__ batch,
                                                    float* __restrict__ part) {
    const int gi = blockIdx.x, rs = blockIdx.y, t = threadIdx.x;
    int lo = 0, hi = NN;
    while (lo < hi) { int mid = (lo + hi) >> 1; if (batch[mid] < gi) lo = mid + 1; else hi = mid; }
    const int start = lo;
    hi = NN;
    while (lo < hi) { int mid = (lo + hi) >> 1; if (batch[mid] < gi + 1) lo = mid + 1; else hi = mid; }
    const int end = lo;
    const int len = end - start;
    const int q = (len + 7) >> 3;
    int r0 = start + rs * q;
    int r1 = r0 + q; if (r1 > end) r1 = end; if (r0 > end) r0 = end;
    float mx0 = -INFINITY, mx1 = -INFINITY, s0 = 0.f, s1 = 0.f;
    int i = r0;
    for (; i + 2 <= r1; i += 2) {
        unsigned int d0 = *(const unsigned int*)(h + (size_t)i * 1024 + t * 2);
        unsigned int d1 = *(const unsigned int*)(h + (size_t)(i + 1) * 1024 + t * 2);
        float v0 = bf16_to_f32((unsigned short)(d0 & 0xFFFFu));
        float v1 = bf16_to_f32((unsigned short)(d0 >> 16));
        float w0 = bf16_to_f32((unsigned short)(d1 & 0xFFFFu));
        float w1 = bf16_to_f32((unsigned short)(d1 >> 16));
        mx0 = fmaxf(mx0, fmaxf(v0, w0)); mx1 = fmaxf(mx1, fmaxf(v1, w1));
        s0 += v0 + w0; s1 += v1 + w1;
    }
    for (; i < r1; ++i) {
        unsigned int d0 = *(const unsigned int*)(h + (size_t)i * 1024 + t * 2);
        float v0 = bf16_to_f32((unsigned short)(d0 & 0xFFFFu));
        float v1 = bf16_to_f32((unsigned short)(d0 >> 16));
        mx0 = fmaxf(mx0, v0); mx1 = fmaxf(mx1, v1);
        s0 += v0; s1 += v1;
    }
    float* p = part + ((size_t)gi * 8 + rs) * 1024;
    p[t * 2] = mx0; p[t * 2 + 1] = mx1;
    p[512 + t * 2] = s0; p[512 + t * 2 + 1] = s1;
}

__global__ __launch_bounds__(256) void pool_combine(const float* __restrict__ part,
                                                    const int* __restrict__ batch,
                                                    float* __restrict__ gT) {
    const int gi = blockIdx.x, t = threadIdx.x;
    int lo = 0, hi = NN;
    while (lo < hi) { int mid = (lo + hi) >> 1; if (batch[mid] < gi) lo = mid + 1; else hi = mid; }
    const int start = lo;
    hi = NN;
    while (lo < hi) { int mid = (lo + hi) >> 1; if (batch[mid] < gi + 1) lo = mid + 1; else hi = mid; }
    int cnt = lo - start; if (cnt < 1) cnt = 1;
    const float inv = 1.0f / (float)cnt;
    float mx0 = -INFINITY, mx1 = -INFINITY, s0 = 0.f, s1 = 0.f;
#pragma unroll
    for (int rs = 0; rs < 8; ++rs) {
        const float* p = part + ((size_t)gi * 8 + rs) * 1024;
        mx0 = fmaxf(mx0, p[t * 2]); mx1 = fmaxf(mx1, p[t * 2 + 1]);
        s0 += p[512 + t * 2]; s1 += p[512 + t * 2 + 1];
    }
    gT[(size_t)(2 * t) * 64 + gi]        = mx0;
    gT[(size_t)(2 * t + 1) * 64 + gi]    = mx1;
    gT[(size_t)(512 + 2 * t) * 64 + gi]  = s0 * inv;
    gT[(size_t)(512 + 2 * t + 1) * 64 + gi] = s1 * inv;
}

// ---------------------------------------------------------------------------
// MLP: split-K fp32 GEMM (LDS-staged) + combine
// ---------------------------------------------------------------------------
__global__ __launch_bounds__(256) void mlp_splitk(const float* __restrict__ ginT, // [K][64]
                                                  const float* __restrict__ W,    // [K][Ndim]
                                                  int Ndim,
                                                  float* __restrict__ partial) {  // [KB][64][Ndim]
    __shared__ float gsT[64][68];
    __shared__ float Ws[64][68];
    const int t = threadIdx.x;
    const int wv = t >> 6, l = t & 63;
    const int nb = blockIdx.x, kb = blockIdx.y;
    const int n0 = nb * 64;
    const int gr = t >> 2;
    const int c4 = (t & 3) * 16;
    float acc[16] = {};
#pragma unroll
    for (int sub = 0; sub < 2; ++sub) {
        const int k0 = kb * 128 + sub * 64;
        __syncthreads();
        {
            const float4* gsrc = (const float4*)(ginT + (size_t)(k0 + gr) * 64 + c4);
            float4* gd = (float4*)&gsT[gr][c4];
            gd[0] = gsrc[0]; gd[1] = gsrc[1]; gd[2] = gsrc[2]; gd[3] = gsrc[3];
            const float4* wsrc = (const float4*)(W + (size_t)(k0 + gr) * Ndim + n0 + c4);
            float4* wd = (float4*)&Ws[gr][c4];
            wd[0] = wsrc[0]; wd[1] = wsrc[1]; wd[2] = wsrc[2]; wd[3] = wsrc[3];
        }
        __syncthreads();
#pragma unroll 4
        for (int kk = 0; kk < 64; ++kk) {
            const float wval = Ws[kk][l];
            const float4* gv = (const float4*)&gsT[kk][wv * 16];
            float4 g0 = gv[0], g1 = gv[1], g2 = gv[2], g3 = gv[3];
            acc[0]  = fmaf(g0.x, wval, acc[0]);  acc[1]  = fmaf(g0.y, wval, acc[1]);
            acc[2]  = fmaf(g0.z, wval, acc[2]);  acc[3]  = fmaf(g0.w, wval, acc[3]);
            acc[4]  = fmaf(g1.x, wval, acc[4]);  acc[5]  = fmaf(g1.y, wval, acc[5]);
            acc[6]  = fmaf(g1.z, wval, acc[6]);  acc[7]  = fmaf(g1.w, wval, acc[7]);
            acc[8]  = fmaf(g2.x, wval, acc[8]);  acc[9]  = fmaf(g2.y, wval, acc[9]);
            acc[10] = fmaf(g2.z, wval, acc[10]); acc[11] = fmaf(g2.w, wval, acc[11]);
            acc[12] = fmaf(g3.x, wval, acc[12]); acc[13] = fmaf(g3.y, wval, acc[13]);
            acc[14] = fmaf(g3.z, wval, acc[14]); acc[15] = fmaf(g3.w, wval, acc[15]);
        }
    }
    float* p = partial + ((size_t)kb * 64) * Ndim;
#pragma unroll
    for (int g = 0; g < 16; ++g)
        p[(size_t)(wv * 16 + g) * Ndim + n0 + l] = acc[g];
}

__global__ __launch_bounds__(256) void mlp_combine(const float* __restrict__ partial, int nparts,
                                                   const float* __restrict__ bias, int Ndim,
                                                   float* __restrict__ outN,
                                                   float* __restrict__ outT) {
    const int idx = blockIdx.x * 256 + threadIdx.x;
    if (idx >= 64 * Ndim) return;
    const int g = idx / Ndim, n = idx - g * Ndim;
    float s = bias[n];
    for (int kb = 0; kb < nparts; ++kb)
        s += partial[((size_t)kb * 64 + g) * Ndim + n];
    const float v = fast_tanh(s);
    if (outN) outN[(size_t)g * Ndim + n] = v;
    if (outT) outT[(size_t)n * 64 + g] = v;
}

// ---------------------------------------------------------------------------
// Head: lane t covers k = t*8..t*8+7; wave butterfly reduce per class.
// ---------------------------------------------------------------------------
__global__ __launch_bounds__(64) void head_kernel(const float* __restrict__ g2,
                                                  const float* __restrict__ W,
                                                  const float* __restrict__ b,
                                                  float* __restrict__ out) {
    const int gi = blockIdx.x, t = threadIdx.x;
    const float4* gp = (const float4*)(g2 + (size_t)gi * HH + t * 8);
    float4 ga = gp[0], gb = gp[1];
    float gv[8] = {ga.x, ga.y, ga.z, ga.w, gb.x, gb.y, gb.z, gb.w};
    float logits[CC];
#pragma unroll
    for (int c = 0; c < CC; ++c) {
        float p = 0.f;
#pragma unroll
        for (int j = 0; j < 8; ++j)
            p = fmaf(gv[j], W[(t * 8 + j) * CC + c], p);
#pragma unroll
        for (int off = 32; off > 0; off >>= 1)
            p += __shfl_xor(p, off, 64);
        logits[c] = p + b[c];
    }
    if (t == 0) {
        float mx = logits[0];
#pragma unroll
        for (int c = 1; c < CC; ++c) mx = fmaxf(mx, logits[c]);
        float s = 0.f;
#pragma unroll
        for (int c = 0; c < CC; ++c) s += expf(logits[c] - mx);
        float lse = mx + logf(s);
#pragma unroll
        for (int c = 0; c < CC; ++c) out[(size_t)gi * CC + c] = logits[c] - lse;
    }
}

// ---------------------------------------------------------------------------
extern "C" void kernel_launch(void* const* d_in, const int* in_sizes, int n_in,
                              void* d_out, int out_size, void* d_ws, size_t ws_size,
                              hipStream_t stream) {
    const float* x       = (const float*)d_in[0];
    const int*   ei      = (const int*)d_in[1];
    const int*   batch   = (const int*)d_in[2];
    const float* w_root0 = (const float*)d_in[3];
    const float* w_rel0  = (const float*)d_in[4];
    const float* b0      = (const float*)d_in[5];
    const float* w_root  = (const float*)d_in[6];
    const float* w_rel   = (const float*)d_in[7];
    const float* bvec    = (const float*)d_in[8];
    const float* lin1_w  = (const float*)d_in[9];
    const float* lin1_b  = (const float*)d_in[10];
    const float* lin2_w  = (const float*)d_in[11];
    const float* lin2_b  = (const float*)d_in[12];
    const float* lin3_w  = (const float*)d_in[13];
    const float* lin3_b  = (const float*)d_in[14];
    float* out = (float*)d_out;

    char* w = (char*)d_ws;
    size_t off = 0;
    auto alloc = [&](size_t bytes) -> char* {
        char* p = w + off;
        off += (bytes + 255) & ~(size_t)255;
        return p;
    };
    unsigned short* Xa  = (unsigned short*)alloc((size_t)NN * 1024 * 2);
    unsigned short* Xb  = (unsigned short*)alloc((size_t)NN * 1024 * 2);
    unsigned short* X0  = (unsigned short*)alloc((size_t)NN * 64 * 2);
    unsigned short* WT0 = (unsigned short*)alloc(512 * 64 * 2);
    unsigned short* WTs = (unsigned short*)alloc((size_t)4 * 512 * 1024 * 2);
    int* counts   = (int*)alloc((size_t)NN * 4);
    int* degHist  = (int*)alloc(256 * 4);
    int* degCursor= (int*)alloc(256 * 4);
    int* rowStart = (int*)alloc((size_t)(NN + 1) * 4);
    int* cursor   = (int*)alloc((size_t)NN * 4);
    int* ssrc     = (int*)alloc((size_t)EE * 4);
    int* perm     = (int*)alloc((size_t)NN * 4);
    int* pDeg     = (int*)alloc((size_t)NN * 4);
    int* pRowStart= (int*)alloc((size_t)(NN + 1) * 4);
    int* pCursor  = (int*)alloc((size_t)NN * 4);
    int* pssrc    = (int*)alloc((size_t)EE * 4);
    float* gbufT  = (float*)alloc((size_t)1024 * 64 * 4);
    float* g1T    = (float*)alloc((size_t)512 * 64 * 4);
    float* g2buf  = (float*)alloc((size_t)GG * 512 * 4);
    float* mlpPart = (float*)alloc((size_t)8 * 64 * 512 * 4);
    float* part   = (float*)X0;   // pool partials alias X0 (dead after layer 0); 2 MB

    const int* esrc = ei;
    const int* edst = ei + EE;

    // weight prep + x cast (merged); CSR build + degree sort (desc) + perm CSR
    prep_all_kernel<<<12416, 256, 0, stream>>>(w_root0, w_rel0, WT0, w_root, w_rel, WTs, x, X0);
    zero_i32<<<130, 256, 0, stream>>>(counts, NN + 256);   // counts + degHist (contiguous)
    hist_kernel<<<2048, 256, 0, stream>>>(edst, counts);
    scan_kernel<<<1, 1024, 0, stream>>>(counts, rowStart, cursor);
    scatter_kernel<<<2048, 256, 0, stream>>>(esrc, edst, cursor, ssrc);
    deg_hist_kernel<<<128, 256, 0, stream>>>(counts, degHist);
    deg_scan_kernel<<<1, 256, 0, stream>>>(degHist, degCursor);
    deg_scatter_kernel<<<128, 256, 0, stream>>>(counts, degCursor, perm, pDeg);
    scan_kernel<<<1, 1024, 0, stream>>>(pDeg, pRowStart, pCursor);
    edge_copy_kernel<<<8192, 256, 0, stream>>>(rowStart, perm, pRowStart, ssrc, pssrc);

    // layer 0: F=32 -> H
    agg_kernel<<<8192, 256, 0, stream>>>(X0, 64, 32, X0 + 32, 64, rowStart, ssrc);
    gemm_bias_tanh<<<dim3(4, 256), 256, 0, stream>>>(X0, 64, 64, WT0, b0, Xa, 1024);

    // layers 1..4: H -> H (alternate Xa/Xb), persistent XCD-affine agg
    agg_slice_kernel<<<2048, 256, 0, stream>>>(Xa, Xa + 512, pRowStart, pssrc, perm);
    gemm_bias_tanh<<<dim3(4, 256), 256, 0, stream>>>(Xa, 1024, 1024, WTs + 0 * 524288, bvec + 0, Xb, 1024);
    agg_slice_kernel<<<2048, 256, 0, stream>>>(Xb, Xb + 512, pRowStart, pssrc, perm);
    gemm_bias_tanh<<<dim3(4, 256), 256, 0, stream>>>(Xb, 1024, 1024, WTs + 1 * 524288, bvec + 512, Xa, 1024);
    agg_slice_kernel<<<2048, 256, 0, stream>>>(Xa, Xa + 512, pRowStart, pssrc, perm);
    gemm_bias_tanh<<<dim3(4, 256), 256, 0, stream>>>(Xa, 1024, 1024, WTs + 2 * 524288, bvec + 1024, Xb, 1024);
    agg_slice_kernel<<<2048, 256, 0, stream>>>(Xb, Xb + 512, pRowStart, pssrc, perm);
    gemm_bias_tanh<<<dim3(4, 256), 256, 0, stream>>>(Xb, 1024, 1024, WTs + 3 * 524288, bvec + 1536, Xa, 1024);

    // pooling + MLP tail (LDS-staged split-K GEMMs)
    pool_partial<<<dim3(GG, 8), 256, 0, stream>>>(Xa, batch, part);
    pool_combine<<<GG, 256, 0, stream>>>(part, batch, gbufT);
    mlp_splitk<<<dim3(8, 8), 256, 0, stream>>>(gbufT, lin1_w, 512, mlpPart);
    mlp_combine<<<128, 256, 0, stream>>>(mlpPart, 8, lin1_b, 512, nullptr, g1T);
    mlp_splitk<<<dim3(8, 4), 256, 0, stream>>>(g1T, lin2_w, 512, mlpPart);
    mlp_combine<<<128, 256, 0, stream>>>(mlpPart, 4, lin2_b, 512, g2buf, nullptr);
    head_kernel<<<GG, 64, 0, stream>>>(g2buf, lin3_w, lin3_b, out);
}

// Round 11
// 638.930 us; speedup vs baseline: 1.0799x; 1.0799x over previous
//
#include <hip/hip_runtime.h>
#include <hip/hip_bf16.h>
#include <math.h>

#define NN 32768
#define EE 524288
#define FF 32
#define HH 512
#define GG 64
#define CC 10

typedef __attribute__((ext_vector_type(8))) short short8;
typedef __attribute__((ext_vector_type(4))) float floatx4;

__device__ __forceinline__ float bf16_to_f32(unsigned short u) {
    union { unsigned int u; float f; } v;
    v.u = ((unsigned int)u) << 16;
    return v.f;
}
__device__ __forceinline__ unsigned short f32_to_bf16(float f) {
    union { float f; unsigned int u; } v;
    v.f = f;
    unsigned int u = v.u;
    u += 0x7FFFu + ((u >> 16) & 1u);   // round-to-nearest-even
    return (unsigned short)(u >> 16);
}
// tanh(x) = 1 - 2/(1+e^{2x});  exact at +-inf, err far below bf16 grid
__device__ __forceinline__ float fast_tanh(float x) {
    float e = __expf(2.0f * x);
    return 1.0f - 2.0f * __builtin_amdgcn_rcpf(e + 1.0f);
}

// ---------------------------------------------------------------------------
// Merged prep: [0,128) WT0, [128,8320) WTs, [8320,12416) X0 cast
// ---------------------------------------------------------------------------
__global__ void prep_all_kernel(const float* __restrict__ wr0, const float* __restrict__ wl0,
                                unsigned short* __restrict__ WT0,
                                const float* __restrict__ wroot, const float* __restrict__ wrel,
                                unsigned short* __restrict__ WTs,
                                const float* __restrict__ x, unsigned short* __restrict__ X0) {
    const int b = blockIdx.x;
    if (b < 128) {
        int t = b * 256 + threadIdx.x;          // 512*64
        int n = t >> 6, k = t & 63;
        float v = (k < 32) ? wr0[k * 512 + n] : wl0[(k - 32) * 512 + n];
        WT0[t] = f32_to_bf16(v);
    } else if (b < 8320) {
        int t = (b - 128) * 256 + threadIdx.x;  // 4*512*1024
        int l = t >> 19;
        int r = t & 524287;
        int n = r >> 10, k = r & 1023;
        float v = (k < 512) ? wroot[(size_t)l * 262144 + k * 512 + n]
                            : wrel[(size_t)l * 262144 + (k - 512) * 512 + n];
        WTs[t] = f32_to_bf16(v);
    } else {
        int t = (b - 8320) * 256 + threadIdx.x; // NN*32
        int i = t >> 5, c = t & 31;
        X0[(size_t)i * 64 + c] = f32_to_bf16(x[t]);
    }
}

// ---------------------------------------------------------------------------
// CSR build (counting sort of edges by dst) + degree-sort of nodes (LPT desc)
// + permuted CSR (sequential pssrc reads in agg).
// ---------------------------------------------------------------------------
__global__ void zero_i32(int* __restrict__ p, int n) {
    int i = blockIdx.x * blockDim.x + threadIdx.x;
    if (i < n) p[i] = 0;
}
__global__ void hist_kernel(const int* __restrict__ dst, int* __restrict__ counts) {
    int e = blockIdx.x * blockDim.x + threadIdx.x;
    if (e < EE) atomicAdd(&counts[dst[e]], 1);
}
__global__ __launch_bounds__(1024) void scan_kernel(const int* __restrict__ counts,
                                                    int* __restrict__ rowStart,
                                                    int* __restrict__ cursor) {
    __shared__ int part[1024];
    const int t = threadIdx.x;
    const int base = t * 32;
    int local[32];
    const int4* cp = (const int4*)(counts + base);
    int s = 0;
#pragma unroll
    for (int ii = 0; ii < 8; ++ii) {
        int4 v = cp[ii];
        local[ii * 4 + 0] = v.x; local[ii * 4 + 1] = v.y;
        local[ii * 4 + 2] = v.z; local[ii * 4 + 3] = v.w;
        s += v.x + v.y + v.z + v.w;
    }
    part[t] = s;
    __syncthreads();
    for (int off = 1; off < 1024; off <<= 1) {
        int v = (t >= off) ? part[t - off] : 0;
        __syncthreads();
        part[t] += v;
        __syncthreads();
    }
    int run = part[t] - s;
#pragma unroll
    for (int i = 0; i < 32; ++i) {
        rowStart[base + i] = run;
        cursor[base + i] = run;
        run += local[i];
    }
    if (t == 1023) rowStart[NN] = run;
}
__global__ void scatter_kernel(const int* __restrict__ src, const int* __restrict__ dst,
                               int* __restrict__ cursor, int* __restrict__ ssrc) {
    int e = blockIdx.x * blockDim.x + threadIdx.x;
    if (e < EE) {
        int p = atomicAdd(&cursor[dst[e]], 1);
        ssrc[p] = src[e];
    }
}
// degree histogram (bin = 255-deg -> descending sort), LDS pre-aggregated
__global__ __launch_bounds__(256) void deg_hist_kernel(const int* __restrict__ counts,
                                                       int* __restrict__ degHist) {
    __shared__ int lh[256];
    lh[threadIdx.x] = 0;
    __syncthreads();
    int i = blockIdx.x * 256 + threadIdx.x;
    int d = counts[i]; if (d > 255) d = 255;
    atomicAdd(&lh[255 - d], 1);
    __syncthreads();
    int v = lh[threadIdx.x];
    if (v) atomicAdd(&degHist[threadIdx.x], v);
}
__global__ __launch_bounds__(256) void deg_scan_kernel(const int* __restrict__ degHist,
                                                       int* __restrict__ degCursor) {
    __shared__ int sh[256];
    const int t = threadIdx.x;
    int own = degHist[t];
    sh[t] = own;
    __syncthreads();
    for (int off = 1; off < 256; off <<= 1) {
        int v = (t >= off) ? sh[t - off] : 0;
        __syncthreads();
        sh[t] += v;
        __syncthreads();
    }
    degCursor[t] = sh[t] - own;   // exclusive prefix
}
// scatter + permuted-degree write (pDeg folded in: one launch fewer)
__global__ __launch_bounds__(256) void deg_scatter_kernel(const int* __restrict__ counts,
                                                          int* __restrict__ degCursor,
                                                          int* __restrict__ perm,
                                                          int* __restrict__ pDeg) {
    __shared__ int lh[256];
    __shared__ int base[256];
    lh[threadIdx.x] = 0;
    __syncthreads();
    int i = blockIdx.x * 256 + threadIdx.x;
    int dtrue = counts[i];
    int d = dtrue > 255 ? 255 : dtrue;
    int bin = 255 - d;
    int lr = atomicAdd(&lh[bin], 1);      // local rank within (block, bin)
    __syncthreads();
    int c = lh[threadIdx.x];
    if (c) base[threadIdx.x] = atomicAdd(&degCursor[threadIdx.x], c);
    __syncthreads();
    int p = base[bin] + lr;
    perm[p] = i;
    pDeg[p] = dtrue;
}
// copy each node's edge list into perm order; 4 nodes/wave x 16 lanes
__global__ __launch_bounds__(256) void edge_copy_kernel(const int* __restrict__ rowStart,
                                                        const int* __restrict__ perm,
                                                        const int* __restrict__ pRowStart,
                                                        const int* __restrict__ ssrc,
                                                        int* __restrict__ pssrc) {
    const int wv = threadIdx.x >> 6, lane = threadIdx.x & 63;
    const int sub = lane >> 4, l16 = lane & 15;
    const int p = blockIdx.x * 16 + wv * 4 + sub;
    const int node = perm[p];
    const int s = rowStart[node], e = rowStart[node + 1];
    const int ns = pRowStart[p];
    for (int j = s + l16; j < e; j += 16) pssrc[ns + (j - s)] = ssrc[j];
}

// ---------------------------------------------------------------------------
__device__ __forceinline__ void acc8(float* a, uint4 d) {
    a[0] += bf16_to_f32((unsigned short)(d.x & 0xFFFFu));
    a[1] += bf16_to_f32((unsigned short)(d.x >> 16));
    a[2] += bf16_to_f32((unsigned short)(d.y & 0xFFFFu));
    a[3] += bf16_to_f32((unsigned short)(d.y >> 16));
    a[4] += bf16_to_f32((unsigned short)(d.z & 0xFFFFu));
    a[5] += bf16_to_f32((unsigned short)(d.z >> 16));
    a[6] += bf16_to_f32((unsigned short)(d.w & 0xFFFFu));
    a[7] += bf16_to_f32((unsigned short)(d.w >> 16));
}

// Generic agg (layer 0, cols=32): one wave per node.
__global__ __launch_bounds__(256) void agg_kernel(const unsigned short* __restrict__ Xh, int ldh,
                                                  int cols, unsigned short* __restrict__ Xagg,
                                                  int ldagg, const int* __restrict__ rowStart,
                                                  const int* __restrict__ ssrc) {
    const int node = blockIdx.x * 4 + (threadIdx.x >> 6);
    const int lane = threadIdx.x & 63;
    const int chunks = cols >> 3;
    if (node >= NN || lane >= chunks) return;
    const int s = rowStart[node];
    const int e = rowStart[node + 1];
    float a[8] = {0.f, 0.f, 0.f, 0.f, 0.f, 0.f, 0.f, 0.f};
    const unsigned short* base = Xh + lane * 8;
    int i = s;
    for (; i + 4 <= e; i += 4) {
        int j0 = ssrc[i], j1 = ssrc[i + 1], j2 = ssrc[i + 2], j3 = ssrc[i + 3];
        uint4 d0 = *(const uint4*)(base + (size_t)j0 * ldh);
        uint4 d1 = *(const uint4*)(base + (size_t)j1 * ldh);
        uint4 d2 = *(const uint4*)(base + (size_t)j2 * ldh);
        uint4 d3 = *(const uint4*)(base + (size_t)j3 * ldh);
        acc8(a, d0); acc8(a, d1); acc8(a, d2); acc8(a, d3);
    }
    for (; i < e; ++i) {
        int j = ssrc[i];
        uint4 d = *(const uint4*)(base + (size_t)j * ldh);
        acc8(a, d);
    }
    unsigned short* out = Xagg + (size_t)node * ldagg + lane * 8;
#pragma unroll
    for (int c = 0; c < 8; ++c) out[c] = f32_to_bf16(a[c]);
}

// ---------------------------------------------------------------------------
// Column-sliced XCD-affine agg (cols=512): 8192 short blocks (dynamic
// backfill beats persistent grid-stride — R10 evidence), permuted CSR.
// ---------------------------------------------------------------------------
__global__ __launch_bounds__(256) void agg_slice_kernel(const unsigned short* __restrict__ Xh,
                                                        unsigned short* __restrict__ Xagg,
                                                        const int* __restrict__ pRowStart,
                                                        const int* __restrict__ pssrc,
                                                        const int* __restrict__ perm) {
    const int slice = blockIdx.x & 7;
    const int nb = blockIdx.x >> 3;
    const int wv = threadIdx.x >> 6;
    const int lane = threadIdx.x & 63;
    const int ln = lane >> 3;
    const int lc = lane & 7;
    const int p = nb * 32 + wv * 8 + ln;
    const int node = perm[p];
    const int colOff = slice * 64 + lc * 8;
    const int s = pRowStart[p];
    const int e = pRowStart[p + 1];
    float a[8] = {0.f, 0.f, 0.f, 0.f, 0.f, 0.f, 0.f, 0.f};
    const unsigned short* base = Xh + colOff;
    int i = s;
    for (; i + 8 <= e; i += 8) {
        int j0 = pssrc[i], j1 = pssrc[i + 1], j2 = pssrc[i + 2], j3 = pssrc[i + 3];
        int j4 = pssrc[i + 4], j5 = pssrc[i + 5], j6 = pssrc[i + 6], j7 = pssrc[i + 7];
        uint4 d0 = *(const uint4*)(base + (size_t)j0 * 1024);
        uint4 d1 = *(const uint4*)(base + (size_t)j1 * 1024);
        uint4 d2 = *(const uint4*)(base + (size_t)j2 * 1024);
        uint4 d3 = *(const uint4*)(base + (size_t)j3 * 1024);
        uint4 d4 = *(const uint4*)(base + (size_t)j4 * 1024);
        uint4 d5 = *(const uint4*)(base + (size_t)j5 * 1024);
        uint4 d6 = *(const uint4*)(base + (size_t)j6 * 1024);
        uint4 d7 = *(const uint4*)(base + (size_t)j7 * 1024);
        acc8(a, d0); acc8(a, d1); acc8(a, d2); acc8(a, d3);
        acc8(a, d4); acc8(a, d5); acc8(a, d6); acc8(a, d7);
    }
    for (; i < e; ++i) {
        int j = pssrc[i];
        uint4 d = *(const uint4*)(base + (size_t)j * 1024);
        acc8(a, d);
    }
    unsigned short* out = Xagg + (size_t)node * 1024 + colOff;
#pragma unroll
    for (int c = 0; c < 8; ++c) out[c] = f32_to_bf16(a[c]);
}

// ---------------------------------------------------------------------------
// bf16 MFMA GEMM: BK=64, XOR-swizzled LDS. Grid dim3(256,4) (R9 config —
// the (4,256) swap was part of the R10 regression).
// ---------------------------------------------------------------------------
__global__ __launch_bounds__(256, 4) void gemm_bias_tanh(const unsigned short* __restrict__ Xin,
                                                         int ldin, int K,
                                                         const unsigned short* __restrict__ WT,
                                                         const float* __restrict__ bias,
                                                         unsigned short* __restrict__ Xout,
                                                         int ldout) {
    __shared__ __align__(16) unsigned short As[128 * 64];
    __shared__ __align__(16) unsigned short Bs[128 * 64];
    const int tid = threadIdx.x;
    const int lane = tid & 63;
    const int wave = tid >> 6;
    const int wm = wave >> 1, wn = wave & 1;
    const int bm = blockIdx.x, bn = blockIdx.y;

    floatx4 acc[4][4] = {};

    const int lrow = lane >> 3;
    const int schunk = (lane & 7) ^ (lrow & 7);
    const unsigned short* Abase = Xin + (size_t)(bm * 128) * ldin;
    const unsigned short* Bbase = WT + (size_t)(bn * 128) * K;
    const int m = lane & 15;
    const int quad = lane >> 4;

    for (int k0 = 0; k0 < K; k0 += 64) {
        __syncthreads();
#pragma unroll
        for (int q = 0; q < 4; ++q) {
            const int rr = q * 32 + wave * 8;
            const int row = rr + lrow;
            const unsigned short* sa = Abase + (size_t)row * ldin + (k0 + schunk * 8);
            const unsigned short* sb = Bbase + (size_t)row * K + (k0 + schunk * 8);
            __builtin_amdgcn_global_load_lds(
                (const __attribute__((address_space(1))) void*)sa,
                (__attribute__((address_space(3))) void*)(&As[rr * 64]), 16, 0, 0);
            __builtin_amdgcn_global_load_lds(
                (const __attribute__((address_space(1))) void*)sb,
                (__attribute__((address_space(3))) void*)(&Bs[rr * 64]), 16, 0, 0);
        }
        __syncthreads();
#pragma unroll
        for (int half = 0; half < 2; ++half) {
            short8 af[4], bfr[4];
#pragma unroll
            for (int t = 0; t < 4; ++t) {
                const int row = wm * 64 + t * 16 + m;
                const int chunk = (half * 4 + quad) ^ (row & 7);
                af[t] = *(const short8*)&As[row * 64 + chunk * 8];
            }
#pragma unroll
            for (int t = 0; t < 4; ++t) {
                const int row = wn * 64 + t * 16 + m;
                const int chunk = (half * 4 + quad) ^ (row & 7);
                bfr[t] = *(const short8*)&Bs[row * 64 + chunk * 8];
            }
#pragma unroll
            for (int mt = 0; mt < 4; ++mt)
#pragma unroll
                for (int nt = 0; nt < 4; ++nt)
                    acc[mt][nt] = __builtin_amdgcn_mfma_f32_16x16x32_bf16(af[mt], bfr[nt],
                                                                          acc[mt][nt], 0, 0, 0);
        }
    }

    const int row0 = bm * 128 + wm * 64;
    const int col0 = bn * 128 + wn * 64;
#pragma unroll
    for (int mt = 0; mt < 4; ++mt) {
#pragma unroll
        for (int nt = 0; nt < 4; ++nt) {
            const int col = col0 + nt * 16 + m;
            const float bv = bias[col];
#pragma unroll
            for (int r = 0; r < 4; ++r) {
                const int row = row0 + mt * 16 + quad * 4 + r;
                float v = fast_tanh(acc[mt][nt][r] + bv);
                Xout[(size_t)row * ldout + col] = f32_to_bf16(v);
            }
        }
    }
}

// ---------------------------------------------------------------------------
// Pooling: 2-stage (8 row-slices); stage 2 writes TRANSPOSED gbufT[f][graph].
// ---------------------------------------------------------------------------
__global__ __launch_bounds__(256) void pool_partial(const unsigned short* __restrict__ h,
                                                    const int* __restrict__ batch,
                                                    float* __restrict__ part) {
    const int gi = blockIdx.x, rs = blockIdx.y, t = threadIdx.x;
    int lo = 0, hi = NN;
    while (lo < hi) { int mid = (lo + hi) >> 1; if (batch[mid] < gi) lo = mid + 1; else hi = mid; }
    const int start = lo;
    hi = NN;
    while (lo < hi) { int mid = (lo + hi) >> 1; if (batch[mid] < gi + 1) lo = mid + 1; else hi = mid; }
    const int end = lo;
    const int len = end - start;
    const int q = (len + 7) >> 3;
    int r0 = start + rs * q;
    int r1 = r0 + q; if (r1 > end) r1 = end; if (r0 > end) r0 = end;
    float mx0 = -INFINITY, mx1 = -INFINITY, s0 = 0.f, s1 = 0.f;
    int i = r0;
    for (; i + 2 <= r1; i += 2) {
        unsigned int d0 = *(const unsigned int*)(h + (size_t)i * 1024 + t * 2);
        unsigned int d1 = *(const unsigned int*)(h + (size_t)(i + 1) * 1024 + t * 2);
        float v0 = bf16_to_f32((unsigned short)(d0 & 0xFFFFu));
        float v1 = bf16_to_f32((unsigned short)(d0 >> 16));
        float w0 = bf16_to_f32((unsigned short)(d1 & 0xFFFFu));
        float w1 = bf16_to_f32((unsigned short)(d1 >> 16));
        mx0 = fmaxf(mx0, fmaxf(v0, w0)); mx1 = fmaxf(mx1, fmaxf(v1, w1));
        s0 += v0 + w0; s1 += v1 + w1;
    }
    for (; i < r1; ++i) {
        unsigned int d0 = *(const unsigned int*)(h + (size_t)i * 1024 + t * 2);
        float v0 = bf16_to_f32((unsigned short)(d0 & 0xFFFFu));
        float v1 = bf16_to_f32((unsigned short)(d0 >> 16));
        mx0 = fmaxf(mx0, v0); mx1 = fmaxf(mx1, v1);
        s0 += v0; s1 += v1;
    }
    float* p = part + ((size_t)gi * 8 + rs) * 1024;
    p[t * 2] = mx0; p[t * 2 + 1] = mx1;
    p[512 + t * 2] = s0; p[512 + t * 2 + 1] = s1;
}

__global__ __launch_bounds__(256) void pool_combine(const float* __restrict__ part,
                                                    const int* __restrict__ batch,
                                                    float* __restrict__ gT) {
    const int gi = blockIdx.x, t = threadIdx.x;
    int lo = 0, hi = NN;
    while (lo < hi) { int mid = (lo + hi) >> 1; if (batch[mid] < gi) lo = mid + 1; else hi = mid; }
    const int start = lo;
    hi = NN;
    while (lo < hi) { int mid = (lo + hi) >> 1; if (batch[mid] < gi + 1) lo = mid + 1; else hi = mid; }
    int cnt = lo - start; if (cnt < 1) cnt = 1;
    const float inv = 1.0f / (float)cnt;
    float mx0 = -INFINITY, mx1 = -INFINITY, s0 = 0.f, s1 = 0.f;
#pragma unroll
    for (int rs = 0; rs < 8; ++rs) {
        const float* p = part + ((size_t)gi * 8 + rs) * 1024;
        mx0 = fmaxf(mx0, p[t * 2]); mx1 = fmaxf(mx1, p[t * 2 + 1]);
        s0 += p[512 + t * 2]; s1 += p[512 + t * 2 + 1];
    }
    gT[(size_t)(2 * t) * 64 + gi]        = mx0;
    gT[(size_t)(2 * t + 1) * 64 + gi]    = mx1;
    gT[(size_t)(512 + 2 * t) * 64 + gi]  = s0 * inv;
    gT[(size_t)(512 + 2 * t + 1) * 64 + gi] = s1 * inv;
}

// ---------------------------------------------------------------------------
// MLP: split-K fp32 GEMM (LDS-staged) + combine
// ---------------------------------------------------------------------------
__global__ __launch_bounds__(256) void mlp_splitk(const float* __restrict__ ginT, // [K][64]
                                                  const float* __restrict__ W,    // [K][Ndim]
                                                  int Ndim,
                                                  float* __restrict__ partial) {  // [KB][64][Ndim]
    __shared__ float gsT[64][68];
    __shared__ float Ws[64][68];
    const int t = threadIdx.x;
    const int wv = t >> 6, l = t & 63;
    const int nb = blockIdx.x, kb = blockIdx.y;
    const int n0 = nb * 64;
    const int gr = t >> 2;
    const int c4 = (t & 3) * 16;
    float acc[16] = {};
#pragma unroll
    for (int sub = 0; sub < 2; ++sub) {
        const int k0 = kb * 128 + sub * 64;
        __syncthreads();
        {
            const float4* gsrc = (const float4*)(ginT + (size_t)(k0 + gr) * 64 + c4);
            float4* gd = (float4*)&gsT[gr][c4];
            gd[0] = gsrc[0]; gd[1] = gsrc[1]; gd[2] = gsrc[2]; gd[3] = gsrc[3];
            const float4* wsrc = (const float4*)(W + (size_t)(k0 + gr) * Ndim + n0 + c4);
            float4* wd = (float4*)&Ws[gr][c4];
            wd[0] = wsrc[0]; wd[1] = wsrc[1]; wd[2] = wsrc[2]; wd[3] = wsrc[3];
        }
        __syncthreads();
#pragma unroll 4
        for (int kk = 0; kk < 64; ++kk) {
            const float wval = Ws[kk][l];
            const float4* gv = (const float4*)&gsT[kk][wv * 16];
            float4 g0 = gv[0], g1 = gv[1], g2 = gv[2], g3 = gv[3];
            acc[0]  = fmaf(g0.x, wval, acc[0]);  acc[1]  = fmaf(g0.y, wval, acc[1]);
            acc[2]  = fmaf(g0.z, wval, acc[2]);  acc[3]  = fmaf(g0.w, wval, acc[3]);
            acc[4]  = fmaf(g1.x, wval, acc[4]);  acc[5]  = fmaf(g1.y, wval, acc[5]);
            acc[6]  = fmaf(g1.z, wval, acc[6]);  acc[7]  = fmaf(g1.w, wval, acc[7]);
            acc[8]  = fmaf(g2.x, wval, acc[8]);  acc[9]  = fmaf(g2.y, wval, acc[9]);
            acc[10] = fmaf(g2.z, wval, acc[10]); acc[11] = fmaf(g2.w, wval, acc[11]);
            acc[12] = fmaf(g3.x, wval, acc[12]); acc[13] = fmaf(g3.y, wval, acc[13]);
            acc[14] = fmaf(g3.z, wval, acc[14]); acc[15] = fmaf(g3.w, wval, acc[15]);
        }
    }
    float* p = partial + ((size_t)kb * 64) * Ndim;
#pragma unroll
    for (int g = 0; g < 16; ++g)
        p[(size_t)(wv * 16 + g) * Ndim + n0 + l] = acc[g];
}

__global__ __launch_bounds__(256) void mlp_combine(const float* __restrict__ partial, int nparts,
                                                   const float* __restrict__ bias, int Ndim,
                                                   float* __restrict__ outN,
                                                   float* __restrict__ outT) {
    const int idx = blockIdx.x * 256 + threadIdx.x;
    if (idx >= 64 * Ndim) return;
    const int g = idx / Ndim, n = idx - g * Ndim;
    float s = bias[n];
    for (int kb = 0; kb < nparts; ++kb)
        s += partial[((size_t)kb * 64 + g) * Ndim + n];
    const float v = fast_tanh(s);
    if (outN) outN[(size_t)g * Ndim + n] = v;
    if (outT) outT[(size_t)n * 64 + g] = v;
}

// ---------------------------------------------------------------------------
// Head: lane t covers k = t*8..t*8+7; wave butterfly reduce per class.
// ---------------------------------------------------------------------------
__global__ __launch_bounds__(64) void head_kernel(const float* __restrict__ g2,
                                                  const float* __restrict__ W,
                                                  const float* __restrict__ b,
                                                  float* __restrict__ out) {
    const int gi = blockIdx.x, t = threadIdx.x;
    const float4* gp = (const float4*)(g2 + (size_t)gi * HH + t * 8);
    float4 ga = gp[0], gb = gp[1];
    float gv[8] = {ga.x, ga.y, ga.z, ga.w, gb.x, gb.y, gb.z, gb.w};
    float logits[CC];
#pragma unroll
    for (int c = 0; c < CC; ++c) {
        float p = 0.f;
#pragma unroll
        for (int j = 0; j < 8; ++j)
            p = fmaf(gv[j], W[(t * 8 + j) * CC + c], p);
#pragma unroll
        for (int off = 32; off > 0; off >>= 1)
            p += __shfl_xor(p, off, 64);
        logits[c] = p + b[c];
    }
    if (t == 0) {
        float mx = logits[0];
#pragma unroll
        for (int c = 1; c < CC; ++c) mx = fmaxf(mx, logits[c]);
        float s = 0.f;
#pragma unroll
        for (int c = 0; c < CC; ++c) s += expf(logits[c] - mx);
        float lse = mx + logf(s);
#pragma unroll
        for (int c = 0; c < CC; ++c) out[(size_t)gi * CC + c] = logits[c] - lse;
    }
}

// ---------------------------------------------------------------------------
extern "C" void kernel_launch(void* const* d_in, const int* in_sizes, int n_in,
                              void* d_out, int out_size, void* d_ws, size_t ws_size,
                              hipStream_t stream) {
    const float* x       = (const float*)d_in[0];
    const int*   ei      = (const int*)d_in[1];
    const int*   batch   = (const int*)d_in[2];
    const float* w_root0 = (const float*)d_in[3];
    const float* w_rel0  = (const float*)d_in[4];
    const float* b0      = (const float*)d_in[5];
    const float* w_root  = (const float*)d_in[6];
    const float* w_rel   = (const float*)d_in[7];
    const float* bvec    = (const float*)d_in[8];
    const float* lin1_w  = (const float*)d_in[9];
    const float* lin1_b  = (const float*)d_in[10];
    const float* lin2_w  = (const float*)d_in[11];
    const float* lin2_b  = (const float*)d_in[12];
    const float* lin3_w  = (const float*)d_in[13];
    const float* lin3_b  = (const float*)d_in[14];
    float* out = (float*)d_out;

    char* w = (char*)d_ws;
    size_t off = 0;
    auto alloc = [&](size_t bytes) -> char* {
        char* p = w + off;
        off += (bytes + 255) & ~(size_t)255;
        return p;
    };
    unsigned short* Xa  = (unsigned short*)alloc((size_t)NN * 1024 * 2);
    unsigned short* Xb  = (unsigned short*)alloc((size_t)NN * 1024 * 2);
    unsigned short* X0  = (unsigned short*)alloc((size_t)NN * 64 * 2);
    unsigned short* WT0 = (unsigned short*)alloc(512 * 64 * 2);
    unsigned short* WTs = (unsigned short*)alloc((size_t)4 * 512 * 1024 * 2);
    int* counts   = (int*)alloc((size_t)NN * 4);
    int* degHist  = (int*)alloc(256 * 4);
    int* degCursor= (int*)alloc(256 * 4);
    int* rowStart = (int*)alloc((size_t)(NN + 1) * 4);
    int* cursor   = (int*)alloc((size_t)NN * 4);
    int* ssrc     = (int*)alloc((size_t)EE * 4);
    int* perm     = (int*)alloc((size_t)NN * 4);
    int* pDeg     = (int*)alloc((size_t)NN * 4);
    int* pRowStart= (int*)alloc((size_t)(NN + 1) * 4);
    int* pCursor  = (int*)alloc((size_t)NN * 4);
    int* pssrc    = (int*)alloc((size_t)EE * 4);
    float* gbufT  = (float*)alloc((size_t)1024 * 64 * 4);
    float* g1T    = (float*)alloc((size_t)512 * 64 * 4);
    float* g2buf  = (float*)alloc((size_t)GG * 512 * 4);
    float* mlpPart = (float*)alloc((size_t)8 * 64 * 512 * 4);
    float* part   = (float*)X0;   // pool partials alias X0 (dead after layer 0); 2 MB

    const int* esrc = ei;
    const int* edst = ei + EE;

    // weight prep + x cast (merged); CSR build + degree sort (desc) + perm CSR
    prep_all_kernel<<<12416, 256, 0, stream>>>(w_root0, w_rel0, WT0, w_root, w_rel, WTs, x, X0);
    zero_i32<<<130, 256, 0, stream>>>(counts, NN + 256);   // counts + degHist (contiguous)
    hist_kernel<<<2048, 256, 0, stream>>>(edst, counts);
    scan_kernel<<<1, 1024, 0, stream>>>(counts, rowStart, cursor);
    scatter_kernel<<<2048, 256, 0, stream>>>(esrc, edst, cursor, ssrc);
    deg_hist_kernel<<<128, 256, 0, stream>>>(counts, degHist);
    deg_scan_kernel<<<1, 256, 0, stream>>>(degHist, degCursor);
    deg_scatter_kernel<<<128, 256, 0, stream>>>(counts, degCursor, perm, pDeg);
    scan_kernel<<<1, 1024, 0, stream>>>(pDeg, pRowStart, pCursor);
    edge_copy_kernel<<<2048, 256, 0, stream>>>(rowStart, perm, pRowStart, ssrc, pssrc);

    // layer 0: F=32 -> H
    agg_kernel<<<8192, 256, 0, stream>>>(X0, 64, 32, X0 + 32, 64, rowStart, ssrc);
    gemm_bias_tanh<<<dim3(256, 4), 256, 0, stream>>>(X0, 64, 64, WT0, b0, Xa, 1024);

    // layers 1..4: H -> H (alternate Xa/Xb), XCD-affine + permuted-CSR agg
    agg_slice_kernel<<<8192, 256, 0, stream>>>(Xa, Xa + 512, pRowStart, pssrc, perm);
    gemm_bias_tanh<<<dim3(256, 4), 256, 0, stream>>>(Xa, 1024, 1024, WTs + 0 * 524288, bvec + 0, Xb, 1024);
    agg_slice_kernel<<<8192, 256, 0, stream>>>(Xb, Xb + 512, pRowStart, pssrc, perm);
    gemm_bias_tanh<<<dim3(256, 4), 256, 0, stream>>>(Xb, 1024, 1024, WTs + 1 * 524288, bvec + 512, Xa, 1024);
    agg_slice_kernel<<<8192, 256, 0, stream>>>(Xa, Xa + 512, pRowStart, pssrc, perm);
    gemm_bias_tanh<<<dim3(256, 4), 256, 0, stream>>>(Xa, 1024, 1024, WTs + 2 * 524288, bvec + 1024, Xb, 1024);
    agg_slice_kernel<<<8192, 256, 0, stream>>>(Xb, Xb + 512, pRowStart, pssrc, perm);
    gemm_bias_tanh<<<dim3(256, 4), 256, 0, stream>>>(Xb, 1024, 1024, WTs + 3 * 524288, bvec + 1536, Xa, 1024);

    // pooling + MLP tail (LDS-staged split-K GEMMs)
    pool_partial<<<dim3(GG, 8), 256, 0, stream>>>(Xa, batch, part);
    pool_combine<<<GG, 256, 0, stream>>>(part, batch, gbufT);
    mlp_splitk<<<dim3(8, 8), 256, 0, stream>>>(gbufT, lin1_w, 512, mlpPart);
    mlp_combine<<<128, 256, 0, stream>>>(mlpPart, 8, lin1_b, 512, nullptr, g1T);
    mlp_splitk<<<dim3(8, 4), 256, 0, stream>>>(g1T, lin2_w, 512, mlpPart);
    mlp_combine<<<128, 256, 0, stream>>>(mlpPart, 4, lin2_b, 512, g2buf, nullptr);
    head_kernel<<<GG, 64, 0, stream>>>(g2buf, lin3_w, lin3_b, out);
}

// Round 12
// 630.080 us; speedup vs baseline: 1.0951x; 1.0140x over previous
//
#include <hip/hip_runtime.h>
#include <hip/hip_bf16.h>
#include <math.h>

#define NN 32768
#define EE 524288
#define FF 32
#define HH 512
#define GG 64
#define CC 10

typedef __attribute__((ext_vector_type(8))) short short8;
typedef __attribute__((ext_vector_type(4))) float floatx4;

__device__ __forceinline__ float bf16_to_f32(unsigned short u) {
    union { unsigned int u; float f; } v;
    v.u = ((unsigned int)u) << 16;
    return v.f;
}
__device__ __forceinline__ unsigned short f32_to_bf16(float f) {
    union { float f; unsigned int u; } v;
    v.f = f;
    unsigned int u = v.u;
    u += 0x7FFFu + ((u >> 16) & 1u);   // round-to-nearest-even
    return (unsigned short)(u >> 16);
}
// tanh(x) = 1 - 2/(1+e^{2x});  exact at +-inf, err far below bf16 grid
__device__ __forceinline__ float fast_tanh(float x) {
    float e = __expf(2.0f * x);
    return 1.0f - 2.0f * __builtin_amdgcn_rcpf(e + 1.0f);
}

// ---------------------------------------------------------------------------
// Merged prep: [0,128) WT0, [128,8320) WTs, [8320,12416) X0 cast
// ---------------------------------------------------------------------------
__global__ void prep_all_kernel(const float* __restrict__ wr0, const float* __restrict__ wl0,
                                unsigned short* __restrict__ WT0,
                                const float* __restrict__ wroot, const float* __restrict__ wrel,
                                unsigned short* __restrict__ WTs,
                                const float* __restrict__ x, unsigned short* __restrict__ X0) {
    const int b = blockIdx.x;
    if (b < 128) {
        int t = b * 256 + threadIdx.x;          // 512*64
        int n = t >> 6, k = t & 63;
        float v = (k < 32) ? wr0[k * 512 + n] : wl0[(k - 32) * 512 + n];
        WT0[t] = f32_to_bf16(v);
    } else if (b < 8320) {
        int t = (b - 128) * 256 + threadIdx.x;  // 4*512*1024
        int l = t >> 19;
        int r = t & 524287;
        int n = r >> 10, k = r & 1023;
        float v = (k < 512) ? wroot[(size_t)l * 262144 + k * 512 + n]
                            : wrel[(size_t)l * 262144 + (k - 512) * 512 + n];
        WTs[t] = f32_to_bf16(v);
    } else {
        int t = (b - 8320) * 256 + threadIdx.x; // NN*32
        int i = t >> 5, c = t & 31;
        X0[(size_t)i * 64 + c] = f32_to_bf16(x[t]);
    }
}

// ---------------------------------------------------------------------------
// CSR build (counting sort of edges by dst) + degree-sort of nodes (LPT desc)
// + permuted CSR (sequential pssrc reads in agg).
// ---------------------------------------------------------------------------
__global__ void zero_i32(int* __restrict__ p, int n) {
    int i = blockIdx.x * blockDim.x + threadIdx.x;
    if (i < n) p[i] = 0;
}
__global__ void hist_kernel(const int* __restrict__ dst, int* __restrict__ counts) {
    int e = blockIdx.x * blockDim.x + threadIdx.x;
    if (e < EE) atomicAdd(&counts[dst[e]], 1);
}
__global__ __launch_bounds__(1024) void scan_kernel(const int* __restrict__ counts,
                                                    int* __restrict__ rowStart,
                                                    int* __restrict__ cursor) {
    __shared__ int part[1024];
    const int t = threadIdx.x;
    const int base = t * 32;
    int local[32];
    const int4* cp = (const int4*)(counts + base);
    int s = 0;
#pragma unroll
    for (int ii = 0; ii < 8; ++ii) {
        int4 v = cp[ii];
        local[ii * 4 + 0] = v.x; local[ii * 4 + 1] = v.y;
        local[ii * 4 + 2] = v.z; local[ii * 4 + 3] = v.w;
        s += v.x + v.y + v.z + v.w;
    }
    part[t] = s;
    __syncthreads();
    for (int off = 1; off < 1024; off <<= 1) {
        int v = (t >= off) ? part[t - off] : 0;
        __syncthreads();
        part[t] += v;
        __syncthreads();
    }
    int run = part[t] - s;
#pragma unroll
    for (int i = 0; i < 32; ++i) {
        rowStart[base + i] = run;
        cursor[base + i] = run;
        run += local[i];
    }
    if (t == 1023) rowStart[NN] = run;
}
__global__ void scatter_kernel(const int* __restrict__ src, const int* __restrict__ dst,
                               int* __restrict__ cursor, int* __restrict__ ssrc) {
    int e = blockIdx.x * blockDim.x + threadIdx.x;
    if (e < EE) {
        int p = atomicAdd(&cursor[dst[e]], 1);
        ssrc[p] = src[e];
    }
}
// degree histogram (bin = 255-deg -> descending sort), LDS pre-aggregated
__global__ __launch_bounds__(256) void deg_hist_kernel(const int* __restrict__ counts,
                                                       int* __restrict__ degHist) {
    __shared__ int lh[256];
    lh[threadIdx.x] = 0;
    __syncthreads();
    int i = blockIdx.x * 256 + threadIdx.x;
    int d = counts[i]; if (d > 255) d = 255;
    atomicAdd(&lh[255 - d], 1);
    __syncthreads();
    int v = lh[threadIdx.x];
    if (v) atomicAdd(&degHist[threadIdx.x], v);
}
__global__ __launch_bounds__(256) void deg_scan_kernel(const int* __restrict__ degHist,
                                                       int* __restrict__ degCursor) {
    __shared__ int sh[256];
    const int t = threadIdx.x;
    int own = degHist[t];
    sh[t] = own;
    __syncthreads();
    for (int off = 1; off < 256; off <<= 1) {
        int v = (t >= off) ? sh[t - off] : 0;
        __syncthreads();
        sh[t] += v;
        __syncthreads();
    }
    degCursor[t] = sh[t] - own;   // exclusive prefix
}
// scatter + permuted-degree write
__global__ __launch_bounds__(256) void deg_scatter_kernel(const int* __restrict__ counts,
                                                          int* __restrict__ degCursor,
                                                          int* __restrict__ perm,
                                                          int* __restrict__ pDeg) {
    __shared__ int lh[256];
    __shared__ int base[256];
    lh[threadIdx.x] = 0;
    __syncthreads();
    int i = blockIdx.x * 256 + threadIdx.x;
    int dtrue = counts[i];
    int d = dtrue > 255 ? 255 : dtrue;
    int bin = 255 - d;
    int lr = atomicAdd(&lh[bin], 1);      // local rank within (block, bin)
    __syncthreads();
    int c = lh[threadIdx.x];
    if (c) base[threadIdx.x] = atomicAdd(&degCursor[threadIdx.x], c);
    __syncthreads();
    int p = base[bin] + lr;
    perm[p] = i;
    pDeg[p] = dtrue;
}
// copy each node's edge list into perm order; 4 nodes/wave x 16 lanes
__global__ __launch_bounds__(256) void edge_copy_kernel(const int* __restrict__ rowStart,
                                                        const int* __restrict__ perm,
                                                        const int* __restrict__ pRowStart,
                                                        const int* __restrict__ ssrc,
                                                        int* __restrict__ pssrc) {
    const int wv = threadIdx.x >> 6, lane = threadIdx.x & 63;
    const int sub = lane >> 4, l16 = lane & 15;
    const int p = blockIdx.x * 16 + wv * 4 + sub;
    const int node = perm[p];
    const int s = rowStart[node], e = rowStart[node + 1];
    const int ns = pRowStart[p];
    for (int j = s + l16; j < e; j += 16) pssrc[ns + (j - s)] = ssrc[j];
}

// ---------------------------------------------------------------------------
__device__ __forceinline__ void acc8(float* a, uint4 d) {
    a[0] += bf16_to_f32((unsigned short)(d.x & 0xFFFFu));
    a[1] += bf16_to_f32((unsigned short)(d.x >> 16));
    a[2] += bf16_to_f32((unsigned short)(d.y & 0xFFFFu));
    a[3] += bf16_to_f32((unsigned short)(d.y >> 16));
    a[4] += bf16_to_f32((unsigned short)(d.z & 0xFFFFu));
    a[5] += bf16_to_f32((unsigned short)(d.z >> 16));
    a[6] += bf16_to_f32((unsigned short)(d.w & 0xFFFFu));
    a[7] += bf16_to_f32((unsigned short)(d.w >> 16));
}

// Generic agg (layer 0, cols=32): one wave per node.
__global__ __launch_bounds__(256) void agg_kernel(const unsigned short* __restrict__ Xh, int ldh,
                                                  int cols, unsigned short* __restrict__ Xagg,
                                                  int ldagg, const int* __restrict__ rowStart,
                                                  const int* __restrict__ ssrc) {
    const int node = blockIdx.x * 4 + (threadIdx.x >> 6);
    const int lane = threadIdx.x & 63;
    const int chunks = cols >> 3;
    if (node >= NN || lane >= chunks) return;
    const int s = rowStart[node];
    const int e = rowStart[node + 1];
    float a[8] = {0.f, 0.f, 0.f, 0.f, 0.f, 0.f, 0.f, 0.f};
    const unsigned short* base = Xh + lane * 8;
    int i = s;
    for (; i + 4 <= e; i += 4) {
        int j0 = ssrc[i], j1 = ssrc[i + 1], j2 = ssrc[i + 2], j3 = ssrc[i + 3];
        uint4 d0 = *(const uint4*)(base + (size_t)j0 * ldh);
        uint4 d1 = *(const uint4*)(base + (size_t)j1 * ldh);
        uint4 d2 = *(const uint4*)(base + (size_t)j2 * ldh);
        uint4 d3 = *(const uint4*)(base + (size_t)j3 * ldh);
        acc8(a, d0); acc8(a, d1); acc8(a, d2); acc8(a, d3);
    }
    for (; i < e; ++i) {
        int j = ssrc[i];
        uint4 d = *(const uint4*)(base + (size_t)j * ldh);
        acc8(a, d);
    }
    unsigned short* out = Xagg + (size_t)node * ldagg + lane * 8;
#pragma unroll
    for (int c = 0; c < 8; ++c) out[c] = f32_to_bf16(a[c]);
}

// ---------------------------------------------------------------------------
// Column-sliced XCD-affine agg v5: 16-deep gather pipeline (2x outstanding
// loads vs v3 — latency-capacity bound per R11 model) + paired-chunk blocks
// (4096 blocks; chunk i & 1023-i -> near-constant per-block work).
// ---------------------------------------------------------------------------
__global__ __launch_bounds__(256) void agg_slice_kernel(const unsigned short* __restrict__ Xh,
                                                        unsigned short* __restrict__ Xagg,
                                                        const int* __restrict__ pRowStart,
                                                        const int* __restrict__ pssrc,
                                                        const int* __restrict__ perm) {
    const int slice = blockIdx.x & 7;
    const int pair = blockIdx.x >> 3;          // 0..511
    const int wv = threadIdx.x >> 6;
    const int lane = threadIdx.x & 63;
    const int ln = lane >> 3;
    const int lc = lane & 7;
    const int colOff = slice * 64 + lc * 8;
    const unsigned short* base = Xh + colOff;
#pragma unroll
    for (int half = 0; half < 2; ++half) {
        const int nb = half ? (1023 - pair) : pair;
        const int p = nb * 32 + wv * 8 + ln;
        const int node = perm[p];
        const int s = pRowStart[p];
        const int e = pRowStart[p + 1];
        float a[8] = {0.f, 0.f, 0.f, 0.f, 0.f, 0.f, 0.f, 0.f};
        int i = s;
        for (; i + 16 <= e; i += 16) {
            uint4 d[16];
#pragma unroll
            for (int u = 0; u < 16; ++u) {
                int j = pssrc[i + u];
                d[u] = *(const uint4*)(base + (size_t)j * 1024);
            }
#pragma unroll
            for (int u = 0; u < 16; ++u) acc8(a, d[u]);
        }
        for (; i + 4 <= e; i += 4) {
            int j0 = pssrc[i], j1 = pssrc[i + 1], j2 = pssrc[i + 2], j3 = pssrc[i + 3];
            uint4 d0 = *(const uint4*)(base + (size_t)j0 * 1024);
            uint4 d1 = *(const uint4*)(base + (size_t)j1 * 1024);
            uint4 d2 = *(const uint4*)(base + (size_t)j2 * 1024);
            uint4 d3 = *(const uint4*)(base + (size_t)j3 * 1024);
            acc8(a, d0); acc8(a, d1); acc8(a, d2); acc8(a, d3);
        }
        for (; i < e; ++i) {
            int j = pssrc[i];
            uint4 d = *(const uint4*)(base + (size_t)j * 1024);
            acc8(a, d);
        }
        unsigned short* out = Xagg + (size_t)node * 1024 + colOff;
#pragma unroll
        for (int c = 0; c < 8; ++c) out[c] = f32_to_bf16(a[c]);
    }
}

// ---------------------------------------------------------------------------
// bf16 MFMA GEMM: BK=64, XOR-swizzled LDS. Grid dim3(256,4) (R9 config).
// ---------------------------------------------------------------------------
__global__ __launch_bounds__(256, 4) void gemm_bias_tanh(const unsigned short* __restrict__ Xin,
                                                         int ldin, int K,
                                                         const unsigned short* __restrict__ WT,
                                                         const float* __restrict__ bias,
                                                         unsigned short* __restrict__ Xout,
                                                         int ldout) {
    __shared__ __align__(16) unsigned short As[128 * 64];
    __shared__ __align__(16) unsigned short Bs[128 * 64];
    const int tid = threadIdx.x;
    const int lane = tid & 63;
    const int wave = tid >> 6;
    const int wm = wave >> 1, wn = wave & 1;
    const int bm = blockIdx.x, bn = blockIdx.y;

    floatx4 acc[4][4] = {};

    const int lrow = lane >> 3;
    const int schunk = (lane & 7) ^ (lrow & 7);
    const unsigned short* Abase = Xin + (size_t)(bm * 128) * ldin;
    const unsigned short* Bbase = WT + (size_t)(bn * 128) * K;
    const int m = lane & 15;
    const int quad = lane >> 4;

    for (int k0 = 0; k0 < K; k0 += 64) {
        __syncthreads();
#pragma unroll
        for (int q = 0; q < 4; ++q) {
            const int rr = q * 32 + wave * 8;
            const int row = rr + lrow;
            const unsigned short* sa = Abase + (size_t)row * ldin + (k0 + schunk * 8);
            const unsigned short* sb = Bbase + (size_t)row * K + (k0 + schunk * 8);
            __builtin_amdgcn_global_load_lds(
                (const __attribute__((address_space(1))) void*)sa,
                (__attribute__((address_space(3))) void*)(&As[rr * 64]), 16, 0, 0);
            __builtin_amdgcn_global_load_lds(
                (const __attribute__((address_space(1))) void*)sb,
                (__attribute__((address_space(3))) void*)(&Bs[rr * 64]), 16, 0, 0);
        }
        __syncthreads();
#pragma unroll
        for (int half = 0; half < 2; ++half) {
            short8 af[4], bfr[4];
#pragma unroll
            for (int t = 0; t < 4; ++t) {
                const int row = wm * 64 + t * 16 + m;
                const int chunk = (half * 4 + quad) ^ (row & 7);
                af[t] = *(const short8*)&As[row * 64 + chunk * 8];
            }
#pragma unroll
            for (int t = 0; t < 4; ++t) {
                const int row = wn * 64 + t * 16 + m;
                const int chunk = (half * 4 + quad) ^ (row & 7);
                bfr[t] = *(const short8*)&Bs[row * 64 + chunk * 8];
            }
#pragma unroll
            for (int mt = 0; mt < 4; ++mt)
#pragma unroll
                for (int nt = 0; nt < 4; ++nt)
                    acc[mt][nt] = __builtin_amdgcn_mfma_f32_16x16x32_bf16(af[mt], bfr[nt],
                                                                          acc[mt][nt], 0, 0, 0);
        }
    }

    const int row0 = bm * 128 + wm * 64;
    const int col0 = bn * 128 + wn * 64;
#pragma unroll
    for (int mt = 0; mt < 4; ++mt) {
#pragma unroll
        for (int nt = 0; nt < 4; ++nt) {
            const int col = col0 + nt * 16 + m;
            const float bv = bias[col];
#pragma unroll
            for (int r = 0; r < 4; ++r) {
                const int row = row0 + mt * 16 + quad * 4 + r;
                float v = fast_tanh(acc[mt][nt][r] + bv);
                Xout[(size_t)row * ldout + col] = f32_to_bf16(v);
            }
        }
    }
}

// ---------------------------------------------------------------------------
// Pooling: 2-stage (8 row-slices); stage 2 writes TRANSPOSED gbufT[f][graph].
// ---------------------------------------------------------------------------
__global__ __launch_bounds__(256) void pool_partial(const unsigned short* __restrict__ h,
                                                    const int* __restrict__ batch,
                                                    float* __restrict__ part) {
    const int gi = blockIdx.x, rs = blockIdx.y, t = threadIdx.x;
    int lo = 0, hi = NN;
    while (lo < hi) { int mid = (lo + hi) >> 1; if (batch[mid] < gi) lo = mid + 1; else hi = mid; }
    const int start = lo;
    hi = NN;
    while (lo < hi) { int mid = (lo + hi) >> 1; if (batch[mid] < gi + 1) lo = mid + 1; else hi = mid; }
    const int end = lo;
    const int len = end - start;
    const int q = (len + 7) >> 3;
    int r0 = start + rs * q;
    int r1 = r0 + q; if (r1 > end) r1 = end; if (r0 > end) r0 = end;
    float mx0 = -INFINITY, mx1 = -INFINITY, s0 = 0.f, s1 = 0.f;
    int i = r0;
    for (; i + 2 <= r1; i += 2) {
        unsigned int d0 = *(const unsigned int*)(h + (size_t)i * 1024 + t * 2);
        unsigned int d1 = *(const unsigned int*)(h + (size_t)(i + 1) * 1024 + t * 2);
        float v0 = bf16_to_f32((unsigned short)(d0 & 0xFFFFu));
        float v1 = bf16_to_f32((unsigned short)(d0 >> 16));
        float w0 = bf16_to_f32((unsigned short)(d1 & 0xFFFFu));
        float w1 = bf16_to_f32((unsigned short)(d1 >> 16));
        mx0 = fmaxf(mx0, fmaxf(v0, w0)); mx1 = fmaxf(mx1, fmaxf(v1, w1));
        s0 += v0 + w0; s1 += v1 + w1;
    }
    for (; i < r1; ++i) {
        unsigned int d0 = *(const unsigned int*)(h + (size_t)i * 1024 + t * 2);
        float v0 = bf16_to_f32((unsigned short)(d0 & 0xFFFFu));
        float v1 = bf16_to_f32((unsigned short)(d0 >> 16));
        mx0 = fmaxf(mx0, v0); mx1 = fmaxf(mx1, v1);
        s0 += v0; s1 += v1;
    }
    float* p = part + ((size_t)gi * 8 + rs) * 1024;
    p[t * 2] = mx0; p[t * 2 + 1] = mx1;
    p[512 + t * 2] = s0; p[512 + t * 2 + 1] = s1;
}

__global__ __launch_bounds__(256) void pool_combine(const float* __restrict__ part,
                                                    const int* __restrict__ batch,
                                                    float* __restrict__ gT) {
    const int gi = blockIdx.x, t = threadIdx.x;
    int lo = 0, hi = NN;
    while (lo < hi) { int mid = (lo + hi) >> 1; if (batch[mid] < gi) lo = mid + 1; else hi = mid; }
    const int start = lo;
    hi = NN;
    while (lo < hi) { int mid = (lo + hi) >> 1; if (batch[mid] < gi + 1) lo = mid + 1; else hi = mid; }
    int cnt = lo - start; if (cnt < 1) cnt = 1;
    const float inv = 1.0f / (float)cnt;
    float mx0 = -INFINITY, mx1 = -INFINITY, s0 = 0.f, s1 = 0.f;
#pragma unroll
    for (int rs = 0; rs < 8; ++rs) {
        const float* p = part + ((size_t)gi * 8 + rs) * 1024;
        mx0 = fmaxf(mx0, p[t * 2]); mx1 = fmaxf(mx1, p[t * 2 + 1]);
        s0 += p[512 + t * 2]; s1 += p[512 + t * 2 + 1];
    }
    gT[(size_t)(2 * t) * 64 + gi]        = mx0;
    gT[(size_t)(2 * t + 1) * 64 + gi]    = mx1;
    gT[(size_t)(512 + 2 * t) * 64 + gi]  = s0 * inv;
    gT[(size_t)(512 + 2 * t + 1) * 64 + gi] = s1 * inv;
}

// ---------------------------------------------------------------------------
// MLP: split-K fp32 GEMM (LDS-staged) + combine
// ---------------------------------------------------------------------------
__global__ __launch_bounds__(256) void mlp_splitk(const float* __restrict__ ginT, // [K][64]
                                                  const float* __restrict__ W,    // [K][Ndim]
                                                  int Ndim,
                                                  float* __restrict__ partial) {  // [KB][64][Ndim]
    __shared__ float gsT[64][68];
    __shared__ float Ws[64][68];
    const int t = threadIdx.x;
    const int wv = t >> 6, l = t & 63;
    const int nb = blockIdx.x, kb = blockIdx.y;
    const int n0 = nb * 64;
    const int gr = t >> 2;
    const int c4 = (t & 3) * 16;
    float acc[16] = {};
#pragma unroll
    for (int sub = 0; sub < 2; ++sub) {
        const int k0 = kb * 128 + sub * 64;
        __syncthreads();
        {
            const float4* gsrc = (const float4*)(ginT + (size_t)(k0 + gr) * 64 + c4);
            float4* gd = (float4*)&gsT[gr][c4];
            gd[0] = gsrc[0]; gd[1] = gsrc[1]; gd[2] = gsrc[2]; gd[3] = gsrc[3];
            const float4* wsrc = (const float4*)(W + (size_t)(k0 + gr) * Ndim + n0 + c4);
            float4* wd = (float4*)&Ws[gr][c4];
            wd[0] = wsrc[0]; wd[1] = wsrc[1]; wd[2] = wsrc[2]; wd[3] = wsrc[3];
        }
        __syncthreads();
#pragma unroll 4
        for (int kk = 0; kk < 64; ++kk) {
            const float wval = Ws[kk][l];
            const float4* gv = (const float4*)&gsT[kk][wv * 16];
            float4 g0 = gv[0], g1 = gv[1], g2 = gv[2], g3 = gv[3];
            acc[0]  = fmaf(g0.x, wval, acc[0]);  acc[1]  = fmaf(g0.y, wval, acc[1]);
            acc[2]  = fmaf(g0.z, wval, acc[2]);  acc[3]  = fmaf(g0.w, wval, acc[3]);
            acc[4]  = fmaf(g1.x, wval, acc[4]);  acc[5]  = fmaf(g1.y, wval, acc[5]);
            acc[6]  = fmaf(g1.z, wval, acc[6]);  acc[7]  = fmaf(g1.w, wval, acc[7]);
            acc[8]  = fmaf(g2.x, wval, acc[8]);  acc[9]  = fmaf(g2.y, wval, acc[9]);
            acc[10] = fmaf(g2.z, wval, acc[10]); acc[11] = fmaf(g2.w, wval, acc[11]);
            acc[12] = fmaf(g3.x, wval, acc[12]); acc[13] = fmaf(g3.y, wval, acc[13]);
            acc[14] = fmaf(g3.z, wval, acc[14]); acc[15] = fmaf(g3.w, wval, acc[15]);
        }
    }
    float* p = partial + ((size_t)kb * 64) * Ndim;
#pragma unroll
    for (int g = 0; g < 16; ++g)
        p[(size_t)(wv * 16 + g) * Ndim + n0 + l] = acc[g];
}

__global__ __launch_bounds__(256) void mlp_combine(const float* __restrict__ partial, int nparts,
                                                   const float* __restrict__ bias, int Ndim,
                                                   float* __restrict__ outN,
                                                   float* __restrict__ outT) {
    const int idx = blockIdx.x * 256 + threadIdx.x;
    if (idx >= 64 * Ndim) return;
    const int g = idx / Ndim, n = idx - g * Ndim;
    float s = bias[n];
    for (int kb = 0; kb < nparts; ++kb)
        s += partial[((size_t)kb * 64 + g) * Ndim + n];
    const float v = fast_tanh(s);
    if (outN) outN[(size_t)g * Ndim + n] = v;
    if (outT) outT[(size_t)n * 64 + g] = v;
}

// ---------------------------------------------------------------------------
// Head: lane t covers k = t*8..t*8+7; wave butterfly reduce per class.
// ---------------------------------------------------------------------------
__global__ __launch_bounds__(64) void head_kernel(const float* __restrict__ g2,
                                                  const float* __restrict__ W,
                                                  const float* __restrict__ b,
                                                  float* __restrict__ out) {
    const int gi = blockIdx.x, t = threadIdx.x;
    const float4* gp = (const float4*)(g2 + (size_t)gi * HH + t * 8);
    float4 ga = gp[0], gb = gp[1];
    float gv[8] = {ga.x, ga.y, ga.z, ga.w, gb.x, gb.y, gb.z, gb.w};
    float logits[CC];
#pragma unroll
    for (int c = 0; c < CC; ++c) {
        float p = 0.f;
#pragma unroll
        for (int j = 0; j < 8; ++j)
            p = fmaf(gv[j], W[(t * 8 + j) * CC + c], p);
#pragma unroll
        for (int off = 32; off > 0; off >>= 1)
            p += __shfl_xor(p, off, 64);
        logits[c] = p + b[c];
    }
    if (t == 0) {
        float mx = logits[0];
#pragma unroll
        for (int c = 1; c < CC; ++c) mx = fmaxf(mx, logits[c]);
        float s = 0.f;
#pragma unroll
        for (int c = 0; c < CC; ++c) s += expf(logits[c] - mx);
        float lse = mx + logf(s);
#pragma unroll
        for (int c = 0; c < CC; ++c) out[(size_t)gi * CC + c] = logits[c] - lse;
    }
}

// ---------------------------------------------------------------------------
extern "C" void kernel_launch(void* const* d_in, const int* in_sizes, int n_in,
                              void* d_out, int out_size, void* d_ws, size_t ws_size,
                              hipStream_t stream) {
    const float* x       = (const float*)d_in[0];
    const int*   ei      = (const int*)d_in[1];
    const int*   batch   = (const int*)d_in[2];
    const float* w_root0 = (const float*)d_in[3];
    const float* w_rel0  = (const float*)d_in[4];
    const float* b0      = (const float*)d_in[5];
    const float* w_root  = (const float*)d_in[6];
    const float* w_rel   = (const float*)d_in[7];
    const float* bvec    = (const float*)d_in[8];
    const float* lin1_w  = (const float*)d_in[9];
    const float* lin1_b  = (const float*)d_in[10];
    const float* lin2_w  = (const float*)d_in[11];
    const float* lin2_b  = (const float*)d_in[12];
    const float* lin3_w  = (const float*)d_in[13];
    const float* lin3_b  = (const float*)d_in[14];
    float* out = (float*)d_out;

    char* w = (char*)d_ws;
    size_t off = 0;
    auto alloc = [&](size_t bytes) -> char* {
        char* p = w + off;
        off += (bytes + 255) & ~(size_t)255;
        return p;
    };
    unsigned short* Xa  = (unsigned short*)alloc((size_t)NN * 1024 * 2);
    unsigned short* Xb  = (unsigned short*)alloc((size_t)NN * 1024 * 2);
    unsigned short* X0  = (unsigned short*)alloc((size_t)NN * 64 * 2);
    unsigned short* WT0 = (unsigned short*)alloc(512 * 64 * 2);
    unsigned short* WTs = (unsigned short*)alloc((size_t)4 * 512 * 1024 * 2);
    int* counts   = (int*)alloc((size_t)NN * 4);
    int* degHist  = (int*)alloc(256 * 4);
    int* degCursor= (int*)alloc(256 * 4);
    int* rowStart = (int*)alloc((size_t)(NN + 1) * 4);
    int* cursor   = (int*)alloc((size_t)NN * 4);
    int* ssrc     = (int*)alloc((size_t)EE * 4);
    int* perm     = (int*)alloc((size_t)NN * 4);
    int* pDeg     = (int*)alloc((size_t)NN * 4);
    int* pRowStart= (int*)alloc((size_t)(NN + 1) * 4);
    int* pCursor  = (int*)alloc((size_t)NN * 4);
    int* pssrc    = (int*)alloc((size_t)EE * 4);
    float* gbufT  = (float*)alloc((size_t)1024 * 64 * 4);
    float* g1T    = (float*)alloc((size_t)512 * 64 * 4);
    float* g2buf  = (float*)alloc((size_t)GG * 512 * 4);
    float* mlpPart = (float*)alloc((size_t)8 * 64 * 512 * 4);
    float* part   = (float*)X0;   // pool partials alias X0 (dead after layer 0); 2 MB

    const int* esrc = ei;
    const int* edst = ei + EE;

    // weight prep + x cast (merged); CSR build + degree sort (desc) + perm CSR
    prep_all_kernel<<<12416, 256, 0, stream>>>(w_root0, w_rel0, WT0, w_root, w_rel, WTs, x, X0);
    zero_i32<<<130, 256, 0, stream>>>(counts, NN + 256);   // counts + degHist (contiguous)
    hist_kernel<<<2048, 256, 0, stream>>>(edst, counts);
    scan_kernel<<<1, 1024, 0, stream>>>(counts, rowStart, cursor);
    scatter_kernel<<<2048, 256, 0, stream>>>(esrc, edst, cursor, ssrc);
    deg_hist_kernel<<<128, 256, 0, stream>>>(counts, degHist);
    deg_scan_kernel<<<1, 256, 0, stream>>>(degHist, degCursor);
    deg_scatter_kernel<<<128, 256, 0, stream>>>(counts, degCursor, perm, pDeg);
    scan_kernel<<<1, 1024, 0, stream>>>(pDeg, pRowStart, pCursor);
    edge_copy_kernel<<<2048, 256, 0, stream>>>(rowStart, perm, pRowStart, ssrc, pssrc);

    // layer 0: F=32 -> H
    agg_kernel<<<8192, 256, 0, stream>>>(X0, 64, 32, X0 + 32, 64, rowStart, ssrc);
    gemm_bias_tanh<<<dim3(256, 4), 256, 0, stream>>>(X0, 64, 64, WT0, b0, Xa, 1024);

    // layers 1..4: H -> H (alternate Xa/Xb), XCD-affine paired-chunk agg
    agg_slice_kernel<<<4096, 256, 0, stream>>>(Xa, Xa + 512, pRowStart, pssrc, perm);
    gemm_bias_tanh<<<dim3(256, 4), 256, 0, stream>>>(Xa, 1024, 1024, WTs + 0 * 524288, bvec + 0, Xb, 1024);
    agg_slice_kernel<<<4096, 256, 0, stream>>>(Xb, Xb + 512, pRowStart, pssrc, perm);
    gemm_bias_tanh<<<dim3(256, 4), 256, 0, stream>>>(Xb, 1024, 1024, WTs + 1 * 524288, bvec + 512, Xa, 1024);
    agg_slice_kernel<<<4096, 256, 0, stream>>>(Xa, Xa + 512, pRowStart, pssrc, perm);
    gemm_bias_tanh<<<dim3(256, 4), 256, 0, stream>>>(Xa, 1024, 1024, WTs + 2 * 524288, bvec + 1024, Xb, 1024);
    agg_slice_kernel<<<4096, 256, 0, stream>>>(Xb, Xb + 512, pRowStart, pssrc, perm);
    gemm_bias_tanh<<<dim3(256, 4), 256, 0, stream>>>(Xb, 1024, 1024, WTs + 3 * 524288, bvec + 1536, Xa, 1024);

    // pooling + MLP tail (LDS-staged split-K GEMMs)
    pool_partial<<<dim3(GG, 8), 256, 0, stream>>>(Xa, batch, part);
    pool_combine<<<GG, 256, 0, stream>>>(part, batch, gbufT);
    mlp_splitk<<<dim3(8, 8), 256, 0, stream>>>(gbufT, lin1_w, 512, mlpPart);
    mlp_combine<<<128, 256, 0, stream>>>(mlpPart, 8, lin1_b, 512, nullptr, g1T);
    mlp_splitk<<<dim3(8, 4), 256, 0, stream>>>(g1T, lin2_w, 512, mlpPart);
    mlp_combine<<<128, 256, 0, stream>>>(mlpPart, 4, lin2_b, 512, g2buf, nullptr);
    head_kernel<<<GG, 64, 0, stream>>>(g2buf, lin3_w, lin3_b, out);
}